// Round 8
// baseline (4894.357 us; speedup 1.0000x reference)
//
#include <hip/hip_runtime.h>
#include <hip/hip_bf16.h>

#define N_   128
#define L_   512
#define NB_  4
#define D_   1024
#define H_   16
#define DH_  64
#define IN_  1024
#define T_   512

#define KS_  16      // GEMM K-splits (Kc = 64)
#define NCV_ 32      // attention chunks per sample (16 rows each)
#define NBLK_ 256    // tail megakernel grid (1 block/CU guaranteed resident)

typedef __attribute__((ext_vector_type(8))) short short8v;
typedef __attribute__((ext_vector_type(4))) float float4v;

__device__ __forceinline__ short f2bf(float f) {             // RNE f32->bf16
  unsigned u = __float_as_uint(f);
  u += 0x7FFFu + ((u >> 16) & 1u);
  return (short)(u >> 16);
}
__device__ __forceinline__ int pack2(float a, float b) {
  return (int)(unsigned short)f2bf(a) | ((int)f2bf(b) << 16);
}

// ---------------------------------------------------------------- grid-wide barrier (epoch based)
__device__ __forceinline__ void grid_sync(int* bar) {
  __syncthreads();
  __threadfence();
  if (threadIdx.x == 0) {
    int e = __hip_atomic_load(bar + 1, __ATOMIC_ACQUIRE, __HIP_MEMORY_SCOPE_AGENT);
    int my = __hip_atomic_fetch_add(bar, 1, __ATOMIC_ACQ_REL, __HIP_MEMORY_SCOPE_AGENT);
    if (my == NBLK_ - 1) {
      __hip_atomic_store(bar, 0, __ATOMIC_RELAXED, __HIP_MEMORY_SCOPE_AGENT);
      __hip_atomic_fetch_add(bar + 1, 1, __ATOMIC_RELEASE, __HIP_MEMORY_SCOPE_AGENT);
    } else {
      while (__hip_atomic_load(bar + 1, __ATOMIC_ACQUIRE, __HIP_MEMORY_SCOPE_AGENT) == e)
        __builtin_amdgcn_s_sleep(8);
    }
  }
  __syncthreads();
  __threadfence();
}

// ---------------------------------------------------------------- pos table + barrier zero
__global__ __launch_bounds__(512) void pos_kernel(float* __restrict__ pos, int* __restrict__ bar) {
  if (blockIdx.x == 0 && threadIdx.x < 8) bar[threadIdx.x] = 0;
  int t = blockIdx.x;
  int j = threadIdx.x;
  float seq = (float)(T_ - 1 - t);
  float ex  = (float)(2 * j) * (1.0f / (float)D_);
  float inv = expf(-ex * 9.210340371976184f);
  float si  = seq * inv;
  pos[(size_t)t * D_ + j]        = sinf(si);
  pos[(size_t)t * D_ + 512 + j]  = cosf(si);
}

// ---------------------------------------------------------------- MFMA GEMM unit (128 x 64-col tile, Kc=64)
#define LDA_ 72
template<int NC>
__device__ __forceinline__ void gemm_unit(int ct, int ks,
    const float* __restrict__ A1, const float* __restrict__ B1a, const float* __restrict__ B1b,
    const float* __restrict__ A2, const float* __restrict__ B2a, const float* __restrict__ B2b,
    float* __restrict__ Cpart, short* As, short* Bs) {
  const int tid = threadIdx.x;
  const int colg0 = ct * 64;
  const int k0 = ks * 64;
  const float* B1 = B1a;
  const float* B2 = B2a;
  int col0 = colg0;
  if (NC == 2048 && colg0 >= 1024) { B1 = B1b; B2 = B2b; col0 = colg0 - 1024; }

  const int wid  = tid >> 6;
  const int lane = tid & 63;
  const int lrow = lane & 15;
  const int lk8  = (lane >> 4) * 8;
  const int wrow0 = wid * 32;

  float4v acc[2][4];
  #pragma unroll
  for (int a = 0; a < 2; ++a)
    #pragma unroll
    for (int b = 0; b < 4; ++b)
      acc[a][b] = (float4v){0.f, 0.f, 0.f, 0.f};

  const int arow  = tid >> 1;
  const int ahalf = (tid & 1) * 32;
  const int bcol  = tid & 63;
  const int bkq   = (tid >> 6) * 16;

  const int npass = (A2 != nullptr) ? 2 : 1;
  for (int pass = 0; pass < npass; ++pass) {
    const float* A = pass ? A2 : A1;
    const float* B = pass ? B2 : B1;
    __syncthreads();
    {
      const float* ap = &A[(size_t)arow * D_ + k0 + ahalf];
      short* dst = &As[arow * LDA_ + ahalf];
      #pragma unroll
      for (int j = 0; j < 8; ++j) {
        float4 v = *(const float4*)&ap[4 * j];
        *(int2*)&dst[4 * j] = make_int2(pack2(v.x, v.y), pack2(v.z, v.w));
      }
    }
    {
      int regs[8];
      #pragma unroll
      for (int j = 0; j < 8; ++j) {
        float v0 = B[(size_t)(k0 + bkq + 2 * j) * D_ + col0 + bcol];
        float v1 = B[(size_t)(k0 + bkq + 2 * j + 1) * D_ + col0 + bcol];
        regs[j] = pack2(v0, v1);
      }
      short* dst = &Bs[bcol * LDA_ + bkq];
      *(int4*)&dst[0] = make_int4(regs[0], regs[1], regs[2], regs[3]);
      *(int4*)&dst[8] = make_int4(regs[4], regs[5], regs[6], regs[7]);
    }
    __syncthreads();
    #pragma unroll
    for (int kk = 0; kk < 64; kk += 32) {
      short8v a0 = *(const short8v*)&As[(wrow0 + lrow)      * LDA_ + kk + lk8];
      short8v a1 = *(const short8v*)&As[(wrow0 + 16 + lrow) * LDA_ + kk + lk8];
      #pragma unroll
      for (int ct2 = 0; ct2 < 4; ++ct2) {
        short8v bf = *(const short8v*)&Bs[(ct2 * 16 + lrow) * LDA_ + kk + lk8];
        acc[0][ct2] = __builtin_amdgcn_mfma_f32_16x16x32_bf16(a0, bf, acc[0][ct2], 0, 0, 0);
        acc[1][ct2] = __builtin_amdgcn_mfma_f32_16x16x32_bf16(a1, bf, acc[1][ct2], 0, 0, 0);
      }
    }
  }
  float* Cp = &Cpart[(size_t)ks * (N_ * NC)];
  const int crow = (lane >> 4) * 4;
  const int ccol = lane & 15;
  #pragma unroll
  for (int rt = 0; rt < 2; ++rt)
    #pragma unroll
    for (int ct2 = 0; ct2 < 4; ++ct2)
      #pragma unroll
      for (int j = 0; j < 4; ++j) {
        int row = wrow0 + rt * 16 + crow + j;
        int col = colg0 + ct2 * 16 + ccol;
        Cp[(size_t)row * NC + col] = acc[rt][ct2][j];
      }
}

// ---------------------------------------------------------------- combine units (device)
__device__ __forceinline__ void comb_ew_unit(int unit, const float* __restrict__ Cp,
                                             const float* __restrict__ bias,
                                             float* __restrict__ out, int relu) {
  int idx = unit * 256 + threadIdx.x;
  int col = idx & (D_ - 1);
  float v = 0.f;
  #pragma unroll
  for (int s = 0; s < KS_; ++s) v += Cp[(size_t)s * (N_ * D_) + idx];
  v += bias[col];
  if (relu) v = fmaxf(v, 0.f);
  out[idx] = v;
}

__device__ __forceinline__ void comb_rz_unit(int unit, const float* __restrict__ Cp2,
                                             const float* __restrict__ bg,
                                             const float* __restrict__ xb,
                                             float* __restrict__ rq,
                                             float* __restrict__ zb) {
  int idx = unit * 256 + threadIdx.x;
  int row = idx >> 10, col = idx & (D_ - 1);
  float vr = 0.f, vz = 0.f;
  #pragma unroll
  for (int s = 0; s < KS_; ++s) {
    size_t b = (size_t)s * (N_ * 2048) + (size_t)row * 2048 + col;
    vr += Cp2[b];
    vz += Cp2[b + 1024];
  }
  rq[idx] = (1.f / (1.f + __expf(-vr))) * xb[idx];
  zb[idx] = 1.f / (1.f + __expf(-(vz - bg[col])));
}

// ---------------------------------------------------------------- LN + qk fold (device helper)
__device__ __forceinline__ void ln_qk_epilogue(int n, const float* v4, int tid,
                                               const float* __restrict__ lg,
                                               const float* __restrict__ lb,
                                               const float* __restrict__ Wq,
                                               const float* __restrict__ Wk,
                                               float* __restrict__ qkb,
                                               float* qln, float* Qp) {
  int c = tid * 4;
  float s = v4[0] + v4[1] + v4[2] + v4[3];
  float q = v4[0]*v4[0] + v4[1]*v4[1] + v4[2]*v4[2] + v4[3]*v4[3];
  __shared__ float sa[4], sb[4];
  #pragma unroll
  for (int o = 32; o; o >>= 1) { s += __shfl_xor(s, o, 64); q += __shfl_xor(q, o, 64); }
  if ((tid & 63) == 0) { sa[tid >> 6] = s; sb[tid >> 6] = q; }
  __syncthreads();
  s = sa[0] + sa[1] + sa[2] + sa[3];
  q = sb[0] + sb[1] + sb[2] + sb[3];
  float mean = s * (1.f / D_);
  float var  = q * (1.f / D_) - mean * mean;
  float rstd = rsqrtf(var + 1e-5f);
  #pragma unroll
  for (int j = 0; j < 4; ++j)
    qln[c + j] = (v4[j] - mean) * rstd * lg[c + j] + lb[c + j];
  __syncthreads();
  #pragma unroll
  for (int j = 0; j < 4; ++j) {
    int idx = tid + j * 256; int h = idx >> 6, e = idx & 63;
    float acc = 0.f;
    for (int d = 0; d < DH_; ++d)
      acc += qln[(h << 6) + d] * Wq[((size_t)(h << 6) + d) * DH_ + e];
    Qp[idx] = acc;
  }
  __syncthreads();
  #pragma unroll
  for (int j = 0; j < 4; ++j) {
    int idx = tid + j * 256; int h = idx >> 6, d = idx & 63;
    float acc = 0.f;
    for (int e = 0; e < DH_; ++e)
      acc += Wk[((size_t)(h << 6) + d) * DH_ + e] * Qp[(h << 6) + e];
    qkb[(size_t)n * D_ + idx] = acc * 0.03125f;
  }
}

__device__ __forceinline__ void comb_h_ln_unit(int n, const float* __restrict__ Cp,
                                               const float* __restrict__ zb,
                                               const float* __restrict__ xb,
                                               const float* __restrict__ lg,
                                               const float* __restrict__ lb,
                                               float* __restrict__ h1,
                                               float* __restrict__ hl) {
  int tid = threadIdx.x, c = tid * 4;
  float v[4];
  float s = 0.f, q = 0.f;
  #pragma unroll
  for (int j = 0; j < 4; ++j) {
    float acc = 0.f;
    #pragma unroll
    for (int ss = 0; ss < KS_; ++ss) acc += Cp[(size_t)ss * (N_ * D_) + (size_t)n * D_ + c + j];
    float z = zb[(size_t)n * D_ + c + j];
    float x = xb[(size_t)n * D_ + c + j];
    v[j] = (1.f - z) * x + z * tanhf(acc);
    h1[(size_t)n * D_ + c + j] = v[j];
    s += v[j]; q += v[j] * v[j];
  }
  __shared__ float sa2[4], sb2[4];
  #pragma unroll
  for (int o = 32; o; o >>= 1) { s += __shfl_xor(s, o, 64); q += __shfl_xor(q, o, 64); }
  if ((tid & 63) == 0) { sa2[tid >> 6] = s; sb2[tid >> 6] = q; }
  __syncthreads();
  s = sa2[0] + sa2[1] + sa2[2] + sa2[3];
  q = sb2[0] + sb2[1] + sb2[2] + sb2[3];
  float mean = s * (1.f / D_);
  float var  = q * (1.f / D_) - mean * mean;
  float rstd = rsqrtf(var + 1e-5f);
  #pragma unroll
  for (int j = 0; j < 4; ++j)
    hl[(size_t)n * D_ + c + j] = (v[j] - mean) * rstd * lg[c + j] + lb[c + j];
}

__device__ __forceinline__ void comb_h2_unit(int n, const float* __restrict__ Cp,
                                             const float* __restrict__ zb,
                                             const float* __restrict__ xb,
                                             const float* __restrict__ lg,
                                             const float* __restrict__ lb,
                                             const float* __restrict__ Wq,
                                             const float* __restrict__ Wk,
                                             float* __restrict__ hcur,
                                             float* __restrict__ outp, int slot,
                                             float* __restrict__ qkb,
                                             float* qln, float* Qp) {
  int tid = threadIdx.x, c = tid * 4;
  float v[4];
  #pragma unroll
  for (int j = 0; j < 4; ++j) {
    float acc = 0.f;
    #pragma unroll
    for (int ss = 0; ss < KS_; ++ss) acc += Cp[(size_t)ss * (N_ * D_) + (size_t)n * D_ + c + j];
    float z = zb[(size_t)n * D_ + c + j];
    float x = xb[(size_t)n * D_ + c + j];
    v[j] = (1.f - z) * x + z * tanhf(acc);
    hcur[(size_t)n * D_ + c + j] = v[j];
    size_t bi = (slot >= 0) ? (((size_t)n * NB_ + slot) * D_ + c + j)
                            : ((size_t)n * D_ + c + j);
    outp[bi] = v[j];
  }
  if (Wq != nullptr)
    ln_qk_epilogue(n, v, tid, lg, lb, Wq, Wk, qkb, qln, Qp);
}

__device__ __forceinline__ void attn_fin_unit(int n, const float* __restrict__ pav,
                                              const float* __restrict__ pm,
                                              const float* __restrict__ ps,
                                              const float* __restrict__ Wv,
                                              float* __restrict__ tb, float* att) {
  int tid = threadIdx.x;
  int d0 = tid * 4; int h = tid >> 4;
  float M = -INFINITY;
  for (int c = 0; c < NCV_; ++c) M = fmaxf(M, pm[((size_t)n * NCV_ + c) * H_ + h]);
  float S = 0.f, a0 = 0.f, a1 = 0.f, a2 = 0.f, a3 = 0.f;
  if (M > -INFINITY) {
    for (int c = 0; c < NCV_; ++c) {
      float mc = pm[((size_t)n * NCV_ + c) * H_ + h];
      if (mc == -INFINITY) continue;
      float wgt = __expf(mc - M);
      S += ps[((size_t)n * NCV_ + c) * H_ + h] * wgt;
      size_t ab = ((size_t)n * NCV_ + c) * D_ + d0;
      a0 += pav[ab + 0] * wgt; a1 += pav[ab + 1] * wgt;
      a2 += pav[ab + 2] * wgt; a3 += pav[ab + 3] * wgt;
    }
  }
  float inv = (S > 0.f) ? 1.f / S : 0.f;
  att[d0 + 0] = a0 * inv; att[d0 + 1] = a1 * inv;
  att[d0 + 2] = a2 * inv; att[d0 + 3] = a3 * inv;
  __syncthreads();
  #pragma unroll
  for (int j = 0; j < 4; ++j) {
    int idx = tid + j * 256; int hh = idx >> 6, e = idx & 63;
    float acc = 0.f;
    for (int d = 0; d < DH_; ++d)
      acc += att[(hh << 6) + d] * Wv[((size_t)(hh << 6) + d) * DH_ + e];
    tb[(size_t)n * D_ + idx] = acc;
  }
}

// ---------------------------------------------------------------- layer-tail megakernel
struct TailArgs {
  const float *pav, *pm, *ps, *Wv, *Wo, *bo, *Wfc, *bfc, *ln2g, *ln2b;
  const float *Wr1, *Ur1, *Wz1, *Uz1, *Wg1, *Ug1, *bg1;
  const float *Wr2, *Ur2, *Wz2, *Uz2, *Wg2, *Ug2, *bg2;
  const float *nlg, *nlb, *nWq, *nWk;
  float *hcur, *tb, *ao, *rq, *zb, *h1, *hl, *fwd, *gpart, *qkb, *outp;
  int slot;
  int* bar;
};

__global__ __launch_bounds__(256) void layer_tail(TailArgs a) {
  __shared__ __align__(16) char smem[27648];
  short* As = (short*)smem;
  short* Bs = (short*)(smem + 18432);
  float* att = (float*)smem;
  float* qln = (float*)smem;
  float* Qp  = (float*)(smem + 4096);
  const int b = blockIdx.x;

  // P0: attention merge + V-projection
  if (b < N_) attn_fin_unit(b, a.pav, a.pm, a.ps, a.Wv, a.tb, att);
  grid_sync(a.bar);
  // P1: gemm Wo
  gemm_unit<1024>(b & 15, b >> 4, a.tb, a.Wo, nullptr, nullptr, nullptr, nullptr, a.gpart, As, Bs);
  grid_sync(a.bar);
  // P2: ao = v + bo
  comb_ew_unit(b,        a.gpart, a.bo, a.ao, 0);
  comb_ew_unit(b + 256,  a.gpart, a.bo, a.ao, 0);
  grid_sync(a.bar);
  // P3: gemm RZ1 (2048)
  gemm_unit<2048>(b & 31, b >> 5, a.ao, a.Wr1, a.Wz1, a.hcur, a.Ur1, a.Uz1, a.gpart, As, Bs);
  gemm_unit<2048>((b + 256) & 31, (b + 256) >> 5, a.ao, a.Wr1, a.Wz1, a.hcur, a.Ur1, a.Uz1, a.gpart, As, Bs);
  grid_sync(a.bar);
  // P4: rq/zb
  comb_rz_unit(b,       a.gpart, a.bg1, a.hcur, a.rq, a.zb);
  comb_rz_unit(b + 256, a.gpart, a.bg1, a.hcur, a.rq, a.zb);
  grid_sync(a.bar);
  // P5: gemm h1 = ao@Wg1 + rq@Ug1
  gemm_unit<1024>(b & 15, b >> 4, a.ao, a.Wg1, nullptr, a.rq, a.Ug1, nullptr, a.gpart, As, Bs);
  grid_sync(a.bar);
  // P6: h1 + LN2
  if (b < N_) comb_h_ln_unit(b, a.gpart, a.zb, a.hcur, a.ln2g, a.ln2b, a.h1, a.hl);
  grid_sync(a.bar);
  // P7: gemm fc
  gemm_unit<1024>(b & 15, b >> 4, a.hl, a.Wfc, nullptr, nullptr, nullptr, nullptr, a.gpart, As, Bs);
  grid_sync(a.bar);
  // P8: fwd = relu(v + bfc)
  comb_ew_unit(b,       a.gpart, a.bfc, a.fwd, 1);
  comb_ew_unit(b + 256, a.gpart, a.bfc, a.fwd, 1);
  grid_sync(a.bar);
  // P9: gemm RZ2
  gemm_unit<2048>(b & 31, b >> 5, a.fwd, a.Wr2, a.Wz2, a.h1, a.Ur2, a.Uz2, a.gpart, As, Bs);
  gemm_unit<2048>((b + 256) & 31, (b + 256) >> 5, a.fwd, a.Wr2, a.Wz2, a.h1, a.Ur2, a.Uz2, a.gpart, As, Bs);
  grid_sync(a.bar);
  // P10: rq/zb (GRU2)
  comb_rz_unit(b,       a.gpart, a.bg2, a.h1, a.rq, a.zb);
  comb_rz_unit(b + 256, a.gpart, a.bg2, a.h1, a.rq, a.zb);
  grid_sync(a.bar);
  // P11: gemm h2 = fwd@Wg2 + rq@Ug2
  gemm_unit<1024>(b & 15, b >> 4, a.fwd, a.Wg2, nullptr, a.rq, a.Ug2, nullptr, a.gpart, As, Bs);
  grid_sync(a.bar);
  // P12: hcur/out + optional next-layer LN1+qk
  if (b < N_) comb_h2_unit(b, a.gpart, a.zb, a.h1, a.nlg, a.nlb, a.nWq, a.nWk,
                           a.hcur, a.outp, a.slot, a.qkb, qln, Qp);
}

// ---------------------------------------------------------------- embed gemm (standalone)
__global__ __launch_bounds__(256) void gemm1024_kernel(const float* __restrict__ A,
                                                       const float* __restrict__ B,
                                                       float* __restrict__ Cpart) {
  __shared__ __align__(16) char smem[27648];
  gemm_unit<1024>(blockIdx.x & 15, blockIdx.x >> 4, A, B, nullptr, nullptr, nullptr, nullptr,
                  Cpart, (short*)smem, (short*)(smem + 18432));
}

// ---------------------------------------------------------------- embed combine
__global__ __launch_bounds__(256) void comb_embed_lnqk(const float* __restrict__ Cp,
                                                       const float* __restrict__ bias,
                                                       const float* __restrict__ lg,
                                                       const float* __restrict__ lb,
                                                       const float* __restrict__ Wq,
                                                       const float* __restrict__ Wk,
                                                       float* __restrict__ hcur,
                                                       float* __restrict__ out_li,
                                                       float* __restrict__ qkb) {
  int n = blockIdx.x, tid = threadIdx.x, c = tid * 4;
  __shared__ float qln[D_], Qp[D_];
  float v[4];
  #pragma unroll
  for (int j = 0; j < 4; ++j) {
    float acc = 0.f;
    #pragma unroll
    for (int s = 0; s < KS_; ++s) acc += Cp[(size_t)s * (N_ * D_) + (size_t)n * D_ + c + j];
    v[j] = fmaxf(acc + bias[c + j], 0.f);
    hcur[(size_t)n * D_ + c + j] = v[j];
    out_li[((size_t)n * NB_ + 0) * D_ + c + j] = v[j];
  }
  ln_qk_epilogue(n, v, tid, lg, lb, Wq, Wk, qkb, qln, Qp);
}

// ---------------------------------------------------------------- streaming attention
__global__ __launch_bounds__(256) void attn_stream(
    const float* __restrict__ mem, const float* __restrict__ pos,
    const int* __restrict__ mask, const int* __restrict__ midx,
    const float* __restrict__ qkv, const float* __restrict__ lng,
    const float* __restrict__ lnb, int blk,
    float* __restrict__ pav, float* __restrict__ pm, float* __restrict__ ps)
{
  const int n    = blockIdx.y;
  const int w    = threadIdx.x >> 6;
  const int lane = threadIdx.x & 63;
  const int vc   = blockIdx.x * 4 + w;
  const int l0   = vc * (L_ / NCV_);
  const int d0   = lane * 16;

  float g[16], bv[16], qv[16];
  #pragma unroll
  for (int j = 0; j < 4; ++j) {
    float4 t0 = *(const float4*)&lng[d0 + 4 * j];
    g[4*j+0] = t0.x; g[4*j+1] = t0.y; g[4*j+2] = t0.z; g[4*j+3] = t0.w;
    float4 t1 = *(const float4*)&lnb[d0 + 4 * j];
    bv[4*j+0] = t1.x; bv[4*j+1] = t1.y; bv[4*j+2] = t1.z; bv[4*j+3] = t1.w;
    float4 t2 = *(const float4*)&qkv[(size_t)n * D_ + d0 + 4 * j];
    qv[4*j+0] = t2.x; qv[4*j+1] = t2.y; qv[4*j+2] = t2.z; qv[4*j+3] = t2.w;
  }
  float m_run = -INFINITY, s_run = 0.f;
  float av[16];
  #pragma unroll
  for (int j = 0; j < 16; ++j) av[j] = 0.f;

  for (int l = l0; l < l0 + (L_ / NCV_); ++l) {
    if (mask[(size_t)n * L_ + l] == 0) continue;
    const float* xr = &mem[(((size_t)n * L_ + l) * NB_ + blk) * D_ + d0];
    const int tt = midx[(size_t)n * L_ + l];
    const float* pr = &pos[(size_t)tt * D_ + d0];
    float xv[16];
    #pragma unroll
    for (int j = 0; j < 4; ++j) {
      float4 a = *(const float4*)&xr[4 * j];
      float4 p = *(const float4*)&pr[4 * j];
      xv[4*j+0] = a.x + p.x; xv[4*j+1] = a.y + p.y;
      xv[4*j+2] = a.z + p.z; xv[4*j+3] = a.w + p.w;
    }
    float s1 = 0.f, s2 = 0.f;
    #pragma unroll
    for (int j = 0; j < 16; ++j) { s1 += xv[j]; s2 += xv[j] * xv[j]; }
    #pragma unroll
    for (int o = 32; o; o >>= 1) { s1 += __shfl_xor(s1, o, 64); s2 += __shfl_xor(s2, o, 64); }
    float mean = s1 * (1.f / D_);
    float var  = s2 * (1.f / D_) - mean * mean;
    float rstd = rsqrtf(var + 1e-5f);
    float e = 0.f;
    float y[16];
    #pragma unroll
    for (int j = 0; j < 16; ++j) {
      y[j] = (xv[j] - mean) * rstd * g[j] + bv[j];
      e += y[j] * qv[j];
    }
    e += __shfl_xor(e, 1, 64);
    e += __shfl_xor(e, 2, 64);
    float mn = fmaxf(m_run, e);
    float al = __expf(m_run - mn);
    float pw = __expf(e - mn);
    s_run = s_run * al + pw;
    #pragma unroll
    for (int j = 0; j < 16; ++j) av[j] = av[j] * al + pw * y[j];
    m_run = mn;
  }
  size_t base = ((size_t)n * NCV_ + vc) * D_ + d0;
  #pragma unroll
  for (int j = 0; j < 16; ++j) pav[base + j] = av[j];
  if ((lane & 3) == 0) {
    size_t mb = ((size_t)n * NCV_ + vc) * H_ + (lane >> 2);
    pm[mb] = m_run;
    ps[mb] = s_run;
  }
}

// ----------------------------------------------------------------
extern "C" void kernel_launch(void* const* d_in, const int* in_sizes, int n_in,
                              void* d_out, int out_size, void* d_ws, size_t ws_size,
                              hipStream_t stream) {
  const float* x    = (const float*)d_in[0];
  const float* mem  = (const float*)d_in[1];
  const int*   mask = (const int*)d_in[2];
  const int*   midx = (const int*)d_in[3];
  const float* We   = (const float*)d_in[5];
  const float* be   = (const float*)d_in[6];
  const float* Wq   = (const float*)d_in[7];
  const float* Wk   = (const float*)d_in[8];
  const float* Wv   = (const float*)d_in[9];
  const float* Wo   = (const float*)d_in[10];
  const float* bo   = (const float*)d_in[11];
  const float* Wfc  = (const float*)d_in[12];
  const float* bfc  = (const float*)d_in[13];
  const float* ln1g = (const float*)d_in[14];
  const float* ln1b = (const float*)d_in[15];
  const float* ln2g = (const float*)d_in[16];
  const float* ln2b = (const float*)d_in[17];
  const float* lnkg = (const float*)d_in[18];
  const float* lnkb = (const float*)d_in[19];
  const float* g1w[7]; for (int j = 0; j < 7; ++j) g1w[j] = (const float*)d_in[20 + j];
  const float* g2w[7]; for (int j = 0; j < 7; ++j) g2w[j] = (const float*)d_in[27 + j];
  float* out = (float*)d_out;
  float* out_li = out + (size_t)N_ * D_;

  float* ws   = (float*)d_ws;
  int*   bar  = (int*)ws; ws += 8;
  float* pos  = ws; ws += (size_t)T_ * D_;
  float* hcur = ws; ws += N_ * D_;
  float* qkb  = ws; ws += N_ * D_;
  float* tb   = ws; ws += N_ * D_;
  float* ao   = ws; ws += N_ * D_;
  float* rq   = ws; ws += N_ * D_;
  float* zb   = ws; ws += N_ * D_;
  float* h1   = ws; ws += N_ * D_;
  float* hl   = ws; ws += N_ * D_;
  float* fwd  = ws; ws += N_ * D_;
  float* gpart = ws; ws += (size_t)KS_ * N_ * 2048;
  float* pav   = ws; ws += (size_t)N_ * NCV_ * D_;
  float* pm    = ws; ws += (size_t)N_ * NCV_ * H_;
  float* ps    = ws; ws += (size_t)N_ * NCV_ * H_;

  const dim3 at_grid(NCV_ / 4, N_);

  pos_kernel<<<T_, 512, 0, stream>>>(pos, bar);

  gemm1024_kernel<<<256, 256, 0, stream>>>(x, We, gpart);
  comb_embed_lnqk<<<N_, 256, 0, stream>>>(gpart, be, ln1g, ln1b, Wq, Wk, hcur, out_li, qkb);

  for (int i = 0; i < NB_; ++i) {
    size_t oD  = (size_t)i * D_;
    size_t oDD = (size_t)i * D_ * D_;
    size_t oH  = (size_t)i * H_ * DH_ * DH_;

    attn_stream<<<at_grid, 256, 0, stream>>>(mem, pos, mask, midx, qkb,
                                             lnkg + oD, lnkb + oD, i, pav, pm, ps);

    bool last = (i == NB_ - 1);
    TailArgs a;
    a.pav = pav; a.pm = pm; a.ps = ps;
    a.Wv = Wv + oH; a.Wo = Wo + oDD; a.bo = bo + oD;
    a.Wfc = Wfc + oDD; a.bfc = bfc + oD;
    a.ln2g = ln2g + oD; a.ln2b = ln2b + oD;
    a.Wr1 = g1w[0] + oDD; a.Ur1 = g1w[1] + oDD; a.Wz1 = g1w[2] + oDD; a.Uz1 = g1w[3] + oDD;
    a.Wg1 = g1w[4] + oDD; a.Ug1 = g1w[5] + oDD; a.bg1 = g1w[6] + oD;
    a.Wr2 = g2w[0] + oDD; a.Ur2 = g2w[1] + oDD; a.Wz2 = g2w[2] + oDD; a.Uz2 = g2w[3] + oDD;
    a.Wg2 = g2w[4] + oDD; a.Ug2 = g2w[5] + oDD; a.bg2 = g2w[6] + oD;
    a.nlg = last ? nullptr : (ln1g + oD + D_);
    a.nlb = last ? nullptr : (ln1b + oD + D_);
    a.nWq = last ? nullptr : (Wq + oH + H_ * DH_ * DH_);
    a.nWk = last ? nullptr : (Wk + oH + H_ * DH_ * DH_);
    a.hcur = hcur; a.tb = tb; a.ao = ao; a.rq = rq; a.zb = zb;
    a.h1 = h1; a.hl = hl; a.fwd = fwd; a.gpart = gpart; a.qkb = qkb;
    a.outp = last ? out : out_li;
    a.slot = last ? -1 : (i + 1);
    a.bar = bar;
    layer_tail<<<NBLK_, 256, 0, stream>>>(a);
  }
}

// Round 9
// 803.550 us; speedup vs baseline: 6.0909x; 6.0909x over previous
//
#include <hip/hip_runtime.h>
#include <hip/hip_bf16.h>

#define N_   128
#define L_   512
#define NB_  4
#define D_   1024
#define H_   16
#define DH_  64
#define IN_  1024
#define T_   512

#define KS_  8       // GEMM K-splits (Kc = 128)
#define NCV_ 32      // attention chunks per sample (16 rows each)

typedef __attribute__((ext_vector_type(8))) short short8v;
typedef __attribute__((ext_vector_type(4))) float float4v;

__device__ __forceinline__ short f2bf(float f) {             // RNE f32->bf16
  unsigned u = __float_as_uint(f);
  u += 0x7FFFu + ((u >> 16) & 1u);
  return (short)(u >> 16);
}
__device__ __forceinline__ int pack2(float a, float b) {
  return (int)(unsigned short)f2bf(a) | ((int)f2bf(b) << 16);
}

// ---------------------------------------------------------------- pos table
__global__ __launch_bounds__(512) void pos_kernel(float* __restrict__ pos) {
  int t = blockIdx.x;
  int j = threadIdx.x;
  float seq = (float)(T_ - 1 - t);
  float ex  = (float)(2 * j) * (1.0f / (float)D_);
  float inv = expf(-ex * 9.210340371976184f);
  float si  = seq * inv;
  pos[(size_t)t * D_ + j]        = sinf(si);
  pos[(size_t)t * D_ + 512 + j]  = cosf(si);
}

// ---------------------------------------------------------------- MFMA split-K GEMM partials
// Kc=128 per split, KS_=8 splits. COLW = 32 (NC=1024) or 64 (NC=2048).
// Grid: (32 col-tiles, 8 k-splits) = 256 blocks either way.
#define LDK_ 136   // padded k-row (shorts)
template<int COLW, int NC, bool HAS2>
__global__ __launch_bounds__(256) void gemm_part_t(const float* __restrict__ A1,
                                                   const float* __restrict__ B1a,
                                                   const float* __restrict__ B1b,
                                                   const float* __restrict__ A2,
                                                   const float* __restrict__ B2a,
                                                   const float* __restrict__ B2b,
                                                   float* __restrict__ Cpart) {
  constexpr int KC = 128;
  constexpr int CT = COLW / 16;
  __shared__ short As[N_ * LDK_];
  __shared__ short Bs[COLW * LDK_];
  const int tid = threadIdx.x;
  const int colg0 = blockIdx.x * COLW;
  const int k0 = blockIdx.y * KC;
  const float* B1 = B1a;
  const float* B2 = B2a;
  int col0 = colg0;
  if (NC == 2048 && colg0 >= 1024) { B1 = B1b; B2 = B2b; col0 = colg0 - 1024; }

  const int wid  = tid >> 6;
  const int lane = tid & 63;
  const int lrow = lane & 15;
  const int lk8  = (lane >> 4) * 8;
  const int wrow0 = wid * 32;

  float4v acc[2][CT];
  #pragma unroll
  for (int a = 0; a < 2; ++a)
    #pragma unroll
    for (int b = 0; b < CT; ++b)
      acc[a][b] = (float4v){0.f, 0.f, 0.f, 0.f};

  const int arow  = tid >> 1;             // A: 2 threads/row, 64 k each
  const int ahalf = (tid & 1) * 64;

  #pragma unroll
  for (int pass = 0; pass < (HAS2 ? 2 : 1); ++pass) {
    const float* A = pass ? A2 : A1;
    const float* B = pass ? B2 : B1;
    if (pass) __syncthreads();
    // ---- stage A[0:128, k0:k0+128] -> bf16
    {
      const float* ap = &A[(size_t)arow * D_ + k0 + ahalf];
      short* dst = &As[arow * LDK_ + ahalf];
      #pragma unroll
      for (int j = 0; j < 16; ++j) {
        float4 v = *(const float4*)&ap[4 * j];
        *(int2*)&dst[4 * j] = make_int2(pack2(v.x, v.y), pack2(v.z, v.w));
      }
    }
    // ---- stage B[k0:k0+128, col0:col0+COLW] -> bf16 Bs[col][k]
    if (COLW == 64) {
      const int bcol = tid & 63, bkq = (tid >> 6) * 32;
      int regs[16];
      #pragma unroll
      for (int j = 0; j < 16; ++j) {
        float v0 = B[(size_t)(k0 + bkq + 2 * j) * D_ + col0 + bcol];
        float v1 = B[(size_t)(k0 + bkq + 2 * j + 1) * D_ + col0 + bcol];
        regs[j] = pack2(v0, v1);
      }
      short* dst = &Bs[bcol * LDK_ + bkq];
      *(int4*)&dst[0]  = make_int4(regs[0],  regs[1],  regs[2],  regs[3]);
      *(int4*)&dst[8]  = make_int4(regs[4],  regs[5],  regs[6],  regs[7]);
      *(int4*)&dst[16] = make_int4(regs[8],  regs[9],  regs[10], regs[11]);
      *(int4*)&dst[24] = make_int4(regs[12], regs[13], regs[14], regs[15]);
    } else {
      const int bcol = tid & 31, bkq = (tid >> 5) * 16;
      int regs[8];
      #pragma unroll
      for (int j = 0; j < 8; ++j) {
        float v0 = B[(size_t)(k0 + bkq + 2 * j) * D_ + col0 + bcol];
        float v1 = B[(size_t)(k0 + bkq + 2 * j + 1) * D_ + col0 + bcol];
        regs[j] = pack2(v0, v1);
      }
      short* dst = &Bs[bcol * LDK_ + bkq];
      *(int4*)&dst[0] = make_int4(regs[0], regs[1], regs[2], regs[3]);
      *(int4*)&dst[8] = make_int4(regs[4], regs[5], regs[6], regs[7]);
    }
    __syncthreads();
    // ---- MFMA over 4 k-chunks of 32
    #pragma unroll
    for (int kk = 0; kk < KC; kk += 32) {
      short8v a0 = *(const short8v*)&As[(wrow0 + lrow)      * LDK_ + kk + lk8];
      short8v a1 = *(const short8v*)&As[(wrow0 + 16 + lrow) * LDK_ + kk + lk8];
      #pragma unroll
      for (int ct = 0; ct < CT; ++ct) {
        short8v bf = *(const short8v*)&Bs[(ct * 16 + lrow) * LDK_ + kk + lk8];
        acc[0][ct] = __builtin_amdgcn_mfma_f32_16x16x32_bf16(a0, bf, acc[0][ct], 0, 0, 0);
        acc[1][ct] = __builtin_amdgcn_mfma_f32_16x16x32_bf16(a1, bf, acc[1][ct], 0, 0, 0);
      }
    }
  }
  float* Cp = &Cpart[(size_t)blockIdx.y * (N_ * NC)];
  const int crow = (lane >> 4) * 4;
  const int ccol = lane & 15;
  #pragma unroll
  for (int rt = 0; rt < 2; ++rt)
    #pragma unroll
    for (int ct = 0; ct < CT; ++ct)
      #pragma unroll
      for (int j = 0; j < 4; ++j) {
        int row = wrow0 + rt * 16 + crow + j;
        int col = colg0 + ct * 16 + ccol;
        Cp[(size_t)row * NC + col] = acc[rt][ct][j];
      }
}

// ---------------------------------------------------------------- LN + qk fold (device helper)
__device__ __forceinline__ void ln_qk_epilogue(int n, const float* v4, int tid,
                                               const float* __restrict__ lg,
                                               const float* __restrict__ lb,
                                               const float* __restrict__ Wq,
                                               const float* __restrict__ Wk,
                                               float* __restrict__ qkb,
                                               float* qln, float* Qp) {
  int c = tid * 4;
  float s = v4[0] + v4[1] + v4[2] + v4[3];
  float q = v4[0]*v4[0] + v4[1]*v4[1] + v4[2]*v4[2] + v4[3]*v4[3];
  __shared__ float sa[4], sb[4];
  #pragma unroll
  for (int o = 32; o; o >>= 1) { s += __shfl_xor(s, o, 64); q += __shfl_xor(q, o, 64); }
  if ((tid & 63) == 0) { sa[tid >> 6] = s; sb[tid >> 6] = q; }
  __syncthreads();
  s = sa[0] + sa[1] + sa[2] + sa[3];
  q = sb[0] + sb[1] + sb[2] + sb[3];
  float mean = s * (1.f / D_);
  float var  = q * (1.f / D_) - mean * mean;
  float rstd = rsqrtf(var + 1e-5f);
  #pragma unroll
  for (int j = 0; j < 4; ++j)
    qln[c + j] = (v4[j] - mean) * rstd * lg[c + j] + lb[c + j];
  __syncthreads();
  #pragma unroll
  for (int j = 0; j < 4; ++j) {
    int idx = tid + j * 256; int h = idx >> 6, e = idx & 63;
    float acc = 0.f;
    for (int d = 0; d < DH_; ++d)
      acc += qln[(h << 6) + d] * Wq[((size_t)(h << 6) + d) * DH_ + e];
    Qp[idx] = acc;
  }
  __syncthreads();
  #pragma unroll
  for (int j = 0; j < 4; ++j) {
    int idx = tid + j * 256; int h = idx >> 6, d = idx & 63;
    float acc = 0.f;
    for (int e = 0; e < DH_; ++e)
      acc += Wk[((size_t)(h << 6) + d) * DH_ + e] * Qp[(h << 6) + e];
    qkb[(size_t)n * D_ + idx] = acc * 0.03125f;
  }
}

// ---------------------------------------------------------------- embed combine
__global__ __launch_bounds__(256) void comb_embed_lnqk(const float* __restrict__ Cp,
                                                       const float* __restrict__ bias,
                                                       const float* __restrict__ lg,
                                                       const float* __restrict__ lb,
                                                       const float* __restrict__ Wq,
                                                       const float* __restrict__ Wk,
                                                       float* __restrict__ hcur,
                                                       float* __restrict__ out_li,
                                                       float* __restrict__ qkb) {
  int n = blockIdx.x, tid = threadIdx.x, c = tid * 4;
  __shared__ float qln[D_], Qp[D_];
  float4 a4 = {0.f, 0.f, 0.f, 0.f};
  #pragma unroll
  for (int s = 0; s < KS_; ++s) {
    float4 p = *(const float4*)&Cp[(size_t)s * (N_ * D_) + (size_t)n * D_ + c];
    a4.x += p.x; a4.y += p.y; a4.z += p.z; a4.w += p.w;
  }
  float4 b4 = *(const float4*)&bias[c];
  float v[4] = {fmaxf(a4.x + b4.x, 0.f), fmaxf(a4.y + b4.y, 0.f),
                fmaxf(a4.z + b4.z, 0.f), fmaxf(a4.w + b4.w, 0.f)};
  *(float4*)&hcur[(size_t)n * D_ + c] = *(float4*)v;
  *(float4*)&out_li[((size_t)n * NB_ + 0) * D_ + c] = *(float4*)v;
  ln_qk_epilogue(n, v, tid, lg, lb, Wq, Wk, qkb, qln, Qp);
}

// ---------------------------------------------------------------- streaming attention
__global__ __launch_bounds__(256) void attn_stream(
    const float* __restrict__ mem, const float* __restrict__ pos,
    const int* __restrict__ mask, const int* __restrict__ midx,
    const float* __restrict__ qkv, const float* __restrict__ lng,
    const float* __restrict__ lnb, int blk,
    float* __restrict__ pav, float* __restrict__ pm, float* __restrict__ ps)
{
  const int n    = blockIdx.y;
  const int w    = threadIdx.x >> 6;
  const int lane = threadIdx.x & 63;
  const int vc   = blockIdx.x * 4 + w;
  const int l0   = vc * (L_ / NCV_);
  const int d0   = lane * 16;

  float g[16], bv[16], qv[16];
  #pragma unroll
  for (int j = 0; j < 4; ++j) {
    float4 t0 = *(const float4*)&lng[d0 + 4 * j];
    g[4*j+0] = t0.x; g[4*j+1] = t0.y; g[4*j+2] = t0.z; g[4*j+3] = t0.w;
    float4 t1 = *(const float4*)&lnb[d0 + 4 * j];
    bv[4*j+0] = t1.x; bv[4*j+1] = t1.y; bv[4*j+2] = t1.z; bv[4*j+3] = t1.w;
    float4 t2 = *(const float4*)&qkv[(size_t)n * D_ + d0 + 4 * j];
    qv[4*j+0] = t2.x; qv[4*j+1] = t2.y; qv[4*j+2] = t2.z; qv[4*j+3] = t2.w;
  }
  float m_run = -INFINITY, s_run = 0.f;
  float av[16];
  #pragma unroll
  for (int j = 0; j < 16; ++j) av[j] = 0.f;

  for (int l = l0; l < l0 + (L_ / NCV_); ++l) {
    if (mask[(size_t)n * L_ + l] == 0) continue;
    const float* xr = &mem[(((size_t)n * L_ + l) * NB_ + blk) * D_ + d0];
    const int tt = midx[(size_t)n * L_ + l];
    const float* pr = &pos[(size_t)tt * D_ + d0];
    float xv[16];
    #pragma unroll
    for (int j = 0; j < 4; ++j) {
      float4 a = *(const float4*)&xr[4 * j];
      float4 p = *(const float4*)&pr[4 * j];
      xv[4*j+0] = a.x + p.x; xv[4*j+1] = a.y + p.y;
      xv[4*j+2] = a.z + p.z; xv[4*j+3] = a.w + p.w;
    }
    float s1 = 0.f, s2 = 0.f;
    #pragma unroll
    for (int j = 0; j < 16; ++j) { s1 += xv[j]; s2 += xv[j] * xv[j]; }
    #pragma unroll
    for (int o = 32; o; o >>= 1) { s1 += __shfl_xor(s1, o, 64); s2 += __shfl_xor(s2, o, 64); }
    float mean = s1 * (1.f / D_);
    float var  = s2 * (1.f / D_) - mean * mean;
    float rstd = rsqrtf(var + 1e-5f);
    float e = 0.f;
    float y[16];
    #pragma unroll
    for (int j = 0; j < 16; ++j) {
      y[j] = (xv[j] - mean) * rstd * g[j] + bv[j];
      e += y[j] * qv[j];
    }
    e += __shfl_xor(e, 1, 64);
    e += __shfl_xor(e, 2, 64);
    float mn = fmaxf(m_run, e);
    float al = __expf(m_run - mn);
    float pw = __expf(e - mn);
    s_run = s_run * al + pw;
    #pragma unroll
    for (int j = 0; j < 16; ++j) av[j] = av[j] * al + pw * y[j];
    m_run = mn;
  }
  size_t base = ((size_t)n * NCV_ + vc) * D_ + d0;
  #pragma unroll
  for (int j = 0; j < 16; ++j) pav[base + j] = av[j];
  if ((lane & 3) == 0) {
    size_t mb = ((size_t)n * NCV_ + vc) * H_ + (lane >> 2);
    pm[mb] = m_run;
    ps[mb] = s_run;
  }
}

// ---------------------------------------------------------------- merge chunks + V-projection -> tb
__global__ __launch_bounds__(256) void attn_fin(const float* __restrict__ pav,
                                                const float* __restrict__ pm,
                                                const float* __restrict__ ps,
                                                const float* __restrict__ Wv,
                                                float* __restrict__ tb) {
  int n = blockIdx.x, tid = threadIdx.x;
  int d0 = tid * 4; int h = tid >> 4;
  float M = -INFINITY;
  for (int c = 0; c < NCV_; ++c) M = fmaxf(M, pm[((size_t)n * NCV_ + c) * H_ + h]);
  float S = 0.f, a0 = 0.f, a1 = 0.f, a2 = 0.f, a3 = 0.f;
  if (M > -INFINITY) {
    for (int c = 0; c < NCV_; ++c) {
      float mc = pm[((size_t)n * NCV_ + c) * H_ + h];
      if (mc == -INFINITY) continue;
      float wgt = __expf(mc - M);
      S += ps[((size_t)n * NCV_ + c) * H_ + h] * wgt;
      size_t ab = ((size_t)n * NCV_ + c) * D_ + d0;
      float4 v = *(const float4*)&pav[ab];
      a0 += v.x * wgt; a1 += v.y * wgt; a2 += v.z * wgt; a3 += v.w * wgt;
    }
  }
  float inv = (S > 0.f) ? 1.f / S : 0.f;
  __shared__ float att[D_];
  att[d0 + 0] = a0 * inv; att[d0 + 1] = a1 * inv;
  att[d0 + 2] = a2 * inv; att[d0 + 3] = a3 * inv;
  __syncthreads();
  #pragma unroll
  for (int j = 0; j < 4; ++j) {
    int idx = tid + j * 256; int hh = idx >> 6, e = idx & 63;
    float acc = 0.f;
    for (int d = 0; d < DH_; ++d)
      acc += att[(hh << 6) + d] * Wv[((size_t)(hh << 6) + d) * DH_ + e];
    tb[(size_t)n * D_ + idx] = acc;
  }
}

// ---------------------------------------------------------------- elementwise combine (float4)
__global__ __launch_bounds__(256) void comb_ew(const float* __restrict__ Cp,
                                               const float* __restrict__ bias,
                                               float* __restrict__ out, int mode) {
  int base = (blockIdx.x * 256 + threadIdx.x) * 4;
  int col = base & (D_ - 1);
  float4 a4 = {0.f, 0.f, 0.f, 0.f};
  #pragma unroll
  for (int s = 0; s < KS_; ++s) {
    float4 p = *(const float4*)&Cp[(size_t)s * (N_ * D_) + base];
    a4.x += p.x; a4.y += p.y; a4.z += p.z; a4.w += p.w;
  }
  float4 b4 = *(const float4*)&bias[col];
  a4.x += b4.x; a4.y += b4.y; a4.z += b4.z; a4.w += b4.w;
  if (mode == 0) {
    a4.x = fmaxf(a4.x, 0.f); a4.y = fmaxf(a4.y, 0.f);
    a4.z = fmaxf(a4.z, 0.f); a4.w = fmaxf(a4.w, 0.f);
  }
  *(float4*)&out[base] = a4;
}

// ---------------------------------------------------------------- GRU r,z combine (float4)
__global__ __launch_bounds__(256) void comb_rz(const float* __restrict__ Cp2,
                                               const float* __restrict__ bg,
                                               const float* __restrict__ xb,
                                               float* __restrict__ rq,
                                               float* __restrict__ zb) {
  int base = (blockIdx.x * 256 + threadIdx.x) * 4;
  int row = base >> 10, col = base & (D_ - 1);
  float4 vr = {0.f, 0.f, 0.f, 0.f}, vz = {0.f, 0.f, 0.f, 0.f};
  #pragma unroll
  for (int s = 0; s < KS_; ++s) {
    size_t b = (size_t)s * (N_ * 2048) + (size_t)row * 2048 + col;
    float4 r = *(const float4*)&Cp2[b];
    float4 z = *(const float4*)&Cp2[b + 1024];
    vr.x += r.x; vr.y += r.y; vr.z += r.z; vr.w += r.w;
    vz.x += z.x; vz.y += z.y; vz.z += z.z; vz.w += z.w;
  }
  float4 x4 = *(const float4*)&xb[base];
  float4 g4 = *(const float4*)&bg[col];
  float4 ro, zo;
  ro.x = (1.f / (1.f + __expf(-vr.x))) * x4.x;
  ro.y = (1.f / (1.f + __expf(-vr.y))) * x4.y;
  ro.z = (1.f / (1.f + __expf(-vr.z))) * x4.z;
  ro.w = (1.f / (1.f + __expf(-vr.w))) * x4.w;
  zo.x = 1.f / (1.f + __expf(-(vz.x - g4.x)));
  zo.y = 1.f / (1.f + __expf(-(vz.y - g4.y)));
  zo.z = 1.f / (1.f + __expf(-(vz.z - g4.z)));
  zo.w = 1.f / (1.f + __expf(-(vz.w - g4.w)));
  *(float4*)&rq[base] = ro;
  *(float4*)&zb[base] = zo;
}

// ---------------------------------------------------------------- GRU1 h combine + LN2
__global__ __launch_bounds__(256) void comb_h_ln(const float* __restrict__ Cp,
                                                 const float* __restrict__ zbuf,
                                                 const float* __restrict__ xb,
                                                 const float* __restrict__ lg,
                                                 const float* __restrict__ lb,
                                                 float* __restrict__ h1,
                                                 float* __restrict__ hl) {
  int n = blockIdx.x, tid = threadIdx.x, c = tid * 4;
  float4 a4 = {0.f, 0.f, 0.f, 0.f};
  #pragma unroll
  for (int ss = 0; ss < KS_; ++ss) {
    float4 p = *(const float4*)&Cp[(size_t)ss * (N_ * D_) + (size_t)n * D_ + c];
    a4.x += p.x; a4.y += p.y; a4.z += p.z; a4.w += p.w;
  }
  float4 z4 = *(const float4*)&zbuf[(size_t)n * D_ + c];
  float4 x4 = *(const float4*)&xb[(size_t)n * D_ + c];
  float v[4];
  v[0] = (1.f - z4.x) * x4.x + z4.x * tanhf(a4.x);
  v[1] = (1.f - z4.y) * x4.y + z4.y * tanhf(a4.y);
  v[2] = (1.f - z4.z) * x4.z + z4.z * tanhf(a4.z);
  v[3] = (1.f - z4.w) * x4.w + z4.w * tanhf(a4.w);
  *(float4*)&h1[(size_t)n * D_ + c] = *(float4*)v;
  float s = v[0] + v[1] + v[2] + v[3];
  float q = v[0]*v[0] + v[1]*v[1] + v[2]*v[2] + v[3]*v[3];
  __shared__ float sa[4], sb[4];
  #pragma unroll
  for (int o = 32; o; o >>= 1) { s += __shfl_xor(s, o, 64); q += __shfl_xor(q, o, 64); }
  if ((tid & 63) == 0) { sa[tid >> 6] = s; sb[tid >> 6] = q; }
  __syncthreads();
  s = sa[0] + sa[1] + sa[2] + sa[3];
  q = sb[0] + sb[1] + sb[2] + sb[3];
  float mean = s * (1.f / D_);
  float var  = q * (1.f / D_) - mean * mean;
  float rstd = rsqrtf(var + 1e-5f);
  #pragma unroll
  for (int j = 0; j < 4; ++j)
    hl[(size_t)n * D_ + c + j] = (v[j] - mean) * rstd * lg[c + j] + lb[c + j];
}

// ---------------------------------------------------------------- GRU2 h combine -> hcur, out, optional LN1+qk(next)
__global__ __launch_bounds__(256) void comb_h2_lnqk(const float* __restrict__ Cp,
                                                    const float* __restrict__ zbuf,
                                                    const float* __restrict__ xb,
                                                    const float* __restrict__ lg,
                                                    const float* __restrict__ lb,
                                                    const float* __restrict__ Wq,
                                                    const float* __restrict__ Wk,
                                                    float* __restrict__ hcur,
                                                    float* __restrict__ outp,
                                                    int slot,
                                                    float* __restrict__ qkb) {
  int n = blockIdx.x, tid = threadIdx.x, c = tid * 4;
  __shared__ float qln[D_], Qp[D_];
  float4 a4 = {0.f, 0.f, 0.f, 0.f};
  #pragma unroll
  for (int ss = 0; ss < KS_; ++ss) {
    float4 p = *(const float4*)&Cp[(size_t)ss * (N_ * D_) + (size_t)n * D_ + c];
    a4.x += p.x; a4.y += p.y; a4.z += p.z; a4.w += p.w;
  }
  float4 z4 = *(const float4*)&zbuf[(size_t)n * D_ + c];
  float4 x4 = *(const float4*)&xb[(size_t)n * D_ + c];
  float v[4];
  v[0] = (1.f - z4.x) * x4.x + z4.x * tanhf(a4.x);
  v[1] = (1.f - z4.y) * x4.y + z4.y * tanhf(a4.y);
  v[2] = (1.f - z4.z) * x4.z + z4.z * tanhf(a4.z);
  v[3] = (1.f - z4.w) * x4.w + z4.w * tanhf(a4.w);
  *(float4*)&hcur[(size_t)n * D_ + c] = *(float4*)v;
  size_t bi = (slot >= 0) ? (((size_t)n * NB_ + slot) * D_ + c)
                          : ((size_t)n * D_ + c);
  *(float4*)&outp[bi] = *(float4*)v;
  if (Wq != nullptr)
    ln_qk_epilogue(n, v, tid, lg, lb, Wq, Wk, qkb, qln, Qp);
}

// ----------------------------------------------------------------
extern "C" void kernel_launch(void* const* d_in, const int* in_sizes, int n_in,
                              void* d_out, int out_size, void* d_ws, size_t ws_size,
                              hipStream_t stream) {
  const float* x    = (const float*)d_in[0];
  const float* mem  = (const float*)d_in[1];
  const int*   mask = (const int*)d_in[2];
  const int*   midx = (const int*)d_in[3];
  const float* We   = (const float*)d_in[5];
  const float* be   = (const float*)d_in[6];
  const float* Wq   = (const float*)d_in[7];
  const float* Wk   = (const float*)d_in[8];
  const float* Wv   = (const float*)d_in[9];
  const float* Wo   = (const float*)d_in[10];
  const float* bo   = (const float*)d_in[11];
  const float* Wfc  = (const float*)d_in[12];
  const float* bfc  = (const float*)d_in[13];
  const float* ln1g = (const float*)d_in[14];
  const float* ln1b = (const float*)d_in[15];
  const float* ln2g = (const float*)d_in[16];
  const float* ln2b = (const float*)d_in[17];
  const float* lnkg = (const float*)d_in[18];
  const float* lnkb = (const float*)d_in[19];
  const float* g1w[7]; for (int j = 0; j < 7; ++j) g1w[j] = (const float*)d_in[20 + j];
  const float* g2w[7]; for (int j = 0; j < 7; ++j) g2w[j] = (const float*)d_in[27 + j];
  float* out = (float*)d_out;
  float* out_li = out + (size_t)N_ * D_;

  float* ws   = (float*)d_ws;
  float* pos  = ws; ws += (size_t)T_ * D_;
  float* hcur = ws; ws += N_ * D_;
  float* qkb  = ws; ws += N_ * D_;
  float* tb   = ws; ws += N_ * D_;
  float* ao   = ws; ws += N_ * D_;
  float* rq   = ws; ws += N_ * D_;
  float* zb   = ws; ws += N_ * D_;
  float* h1   = ws; ws += N_ * D_;
  float* hl   = ws; ws += N_ * D_;
  float* fwd  = ws; ws += N_ * D_;
  float* gpart = ws; ws += (size_t)KS_ * N_ * 2048;   // 8 MB
  float* pav   = ws; ws += (size_t)N_ * NCV_ * D_;    // 16 MB
  float* pm    = ws; ws += (size_t)N_ * NCV_ * H_;
  float* ps    = ws; ws += (size_t)N_ * NCV_ * H_;

  const dim3 gp(32, KS_);            // 256 blocks for both GEMM widths
  const dim3 at_grid(NCV_ / 4, N_);

  pos_kernel<<<T_, 512, 0, stream>>>(pos);

  gemm_part_t<32, 1024, false><<<gp, 256, 0, stream>>>(x, We, nullptr, nullptr, nullptr, nullptr, gpart);
  comb_embed_lnqk<<<N_, 256, 0, stream>>>(gpart, be, ln1g, ln1b, Wq, Wk, hcur, out_li, qkb);

  for (int i = 0; i < NB_; ++i) {
    size_t oD  = (size_t)i * D_;
    size_t oDD = (size_t)i * D_ * D_;
    size_t oH  = (size_t)i * H_ * DH_ * DH_;

    attn_stream<<<at_grid, 256, 0, stream>>>(mem, pos, mask, midx, qkb,
                                             lnkg + oD, lnkb + oD, i, pav, pm, ps);
    attn_fin<<<N_, 256, 0, stream>>>(pav, pm, ps, Wv + oH, tb);

    gemm_part_t<32, 1024, false><<<gp, 256, 0, stream>>>(tb, Wo + oDD, nullptr, nullptr, nullptr, nullptr, gpart);
    comb_ew<<<128, 256, 0, stream>>>(gpart, bo + oD, ao, 1);

    // GRU1: x=hcur, y=ao
    gemm_part_t<64, 2048, true><<<gp, 256, 0, stream>>>(ao, g1w[0] + oDD, g1w[2] + oDD,
                                                        hcur, g1w[1] + oDD, g1w[3] + oDD, gpart);
    comb_rz<<<128, 256, 0, stream>>>(gpart, g1w[6] + oD, hcur, rq, zb);
    gemm_part_t<32, 1024, true><<<gp, 256, 0, stream>>>(ao, g1w[4] + oDD, nullptr,
                                                        rq, g1w[5] + oDD, nullptr, gpart);
    comb_h_ln<<<N_, 256, 0, stream>>>(gpart, zb, hcur, ln2g + oD, ln2b + oD, h1, hl);

    gemm_part_t<32, 1024, false><<<gp, 256, 0, stream>>>(hl, Wfc + oDD, nullptr, nullptr, nullptr, nullptr, gpart);
    comb_ew<<<128, 256, 0, stream>>>(gpart, bfc + oD, fwd, 0);

    // GRU2: x=h1, y=fwd
    gemm_part_t<64, 2048, true><<<gp, 256, 0, stream>>>(fwd, g2w[0] + oDD, g2w[2] + oDD,
                                                        h1, g2w[1] + oDD, g2w[3] + oDD, gpart);
    comb_rz<<<128, 256, 0, stream>>>(gpart, g2w[6] + oD, h1, rq, zb);
    gemm_part_t<32, 1024, true><<<gp, 256, 0, stream>>>(fwd, g2w[4] + oDD, nullptr,
                                                        rq, g2w[5] + oDD, nullptr, gpart);

    bool last = (i == NB_ - 1);
    float* outp = last ? out : out_li;
    int slot = last ? -1 : (i + 1);
    const float* nWq = last ? nullptr : (Wq + oH + H_ * DH_ * DH_);
    const float* nWk = last ? nullptr : (Wk + oH + H_ * DH_ * DH_);
    const float* nlg = last ? nullptr : (ln1g + oD + D_);
    const float* nlb = last ? nullptr : (ln1b + oD + D_);
    comb_h2_lnqk<<<N_, 256, 0, stream>>>(gpart, zb, h1, nlg, nlb, nWq, nWk,
                                         hcur, outp, slot, qkb);
  }
}